// Round 7
// baseline (502.078 us; speedup 1.0000x reference)
//
#include <hip/hip_runtime.h>
#include <hip/hip_cooperative_groups.h>
#include <stdint.h>

#define NB 32
#define SEQ 128
#define EMB 128
#define NSTEP 127
#define NS 512

__device__ __forceinline__ float ftanh(float x){ float e=__expf(2.f*x); return 1.f-2.f/(e+1.f); }
__device__ __forceinline__ float fsig(float x){ return 1.f/(1.f+__expf(-x)); }
__device__ __forceinline__ float4 ld4(const float* p){ return *(const float4*)p; }

// ---------------------------------------------------------------------------
// FMA4 + gemmKS: 512-thr K-split streamed-WT GEMM (unchanged from round 5/6).
// NAMED register double groups only — any VGPR array with non-constant index
// is demoted to scratch (prior session: 256 VGPR + 554 MB scratch traffic).
// ---------------------------------------------------------------------------
#define FMA4(acc, xv, a0, a1, a2, a3) \
  acc.x = fmaf(xv.x, a0.x, fmaf(xv.y, a1.x, fmaf(xv.z, a2.x, fmaf(xv.w, a3.x, acc.x)))); \
  acc.y = fmaf(xv.x, a0.y, fmaf(xv.y, a1.y, fmaf(xv.z, a2.y, fmaf(xv.w, a3.y, acc.y)))); \
  acc.z = fmaf(xv.x, a0.z, fmaf(xv.y, a1.z, fmaf(xv.z, a2.z, fmaf(xv.w, a3.z, acc.z)))); \
  acc.w = fmaf(xv.x, a0.w, fmaf(xv.y, a1.w, fmaf(xv.z, a2.w, fmaf(xv.w, a3.w, acc.w))));

template<int K, int XS>
__device__ __forceinline__ void gemmKS(const float* __restrict__ WT, int NEtot,
                                       const float* Xl, const float* __restrict__ bias,
                                       float* outb, float* partb)
{
  const int tid = threadIdx.x;
  const int et = tid & 31;
  const int kt = (tid >> 5) & 1;
  const int rg = tid >> 6;                 // 0..7
  constexpr int KH = K/2;
  constexpr int G  = KH/4;
  const float* wp = WT + (size_t)kt*KH*NEtot + et*4;
  const float* xr = Xl + (size_t)(rg*2)*XS + kt*KH;
  float4 a0 = {0.f,0.f,0.f,0.f};
  float4 a1 = {0.f,0.f,0.f,0.f};
  float4 w0 = ld4(wp);
  float4 w1 = ld4(wp + NEtot);
  float4 w2 = ld4(wp + 2*NEtot);
  float4 w3 = ld4(wp + 3*NEtot);
  const float* wq = wp + (size_t)4*NEtot;
  float4 m0 = ld4(wq);
  float4 m1 = ld4(wq + NEtot);
  float4 m2 = ld4(wq + 2*NEtot);
  float4 m3 = ld4(wq + 3*NEtot);
  #pragma unroll 2
  for (int g = 0; g + 2 < G; g += 2) {
    const float* wa = wp + (size_t)(4*(g+2))*NEtot;
    float4 n0 = ld4(wa);
    float4 n1 = ld4(wa + NEtot);
    float4 n2 = ld4(wa + 2*NEtot);
    float4 n3 = ld4(wa + 3*NEtot);
    float4 xa0 = ld4(xr + 4*g);
    float4 xa1 = ld4(xr + XS + 4*g);
    FMA4(a0, xa0, w0, w1, w2, w3);
    FMA4(a1, xa1, w0, w1, w2, w3);
    w0=n0; w1=n1; w2=n2; w3=n3;
    const float* wb = wp + (size_t)(4*(g+3))*NEtot;
    float4 o0 = ld4(wb);
    float4 o1 = ld4(wb + NEtot);
    float4 o2 = ld4(wb + 2*NEtot);
    float4 o3 = ld4(wb + 3*NEtot);
    float4 xb0 = ld4(xr + 4*(g+1));
    float4 xb1 = ld4(xr + XS + 4*(g+1));
    FMA4(a0, xb0, m0, m1, m2, m3);
    FMA4(a1, xb1, m0, m1, m2, m3);
    m0=o0; m1=o1; m2=o2; m3=o3;
  }
  {
    float4 xa0 = ld4(xr + 4*(G-2));
    float4 xa1 = ld4(xr + XS + 4*(G-2));
    FMA4(a0, xa0, w0, w1, w2, w3);
    FMA4(a1, xa1, w0, w1, w2, w3);
    float4 xb0 = ld4(xr + 4*(G-1));
    float4 xb1 = ld4(xr + XS + 4*(G-1));
    FMA4(a0, xb0, m0, m1, m2, m3);
    FMA4(a1, xb1, m0, m1, m2, m3);
  }
  float* dst;
  if (kt == 0) {
    float4 bb = ld4(bias + et*4);
    a0.x+=bb.x; a0.y+=bb.y; a0.z+=bb.z; a0.w+=bb.w;
    a1.x+=bb.x; a1.y+=bb.y; a1.z+=bb.z; a1.w+=bb.w;
    dst = outb;
  } else {
    dst = partb;
  }
  float* ob = dst + (size_t)(rg*2)*132 + et*4;
  *(float4*)(ob)       = a0;
  *(float4*)(ob + 132) = a1;
}

// ---------------------------------------------------------------------------
// KParams: single by-value arg for the cooperative kernel (264B kernarg).
// ---------------------------------------------------------------------------
struct KParams {
  const int *question, *response, *maskp, *q_neighbors, *s_neighbors;
  const float *emb_q, *emb_s, *emb_r;
  const float *W_agg, *W_last, *W_query, *W_ih, *b_ih, *b_hh, *b_agg,
              *b_last, *b_query, *w_W;
  float *WT012, *WLT, *WQT, *WIHT, *ER2, *BIH, *CPAD, *E1, *G1, *E2,
        *Hfull, *Cq;
  int *nsel;
  unsigned long long *mwords;
  int *Pmaxi;
};

// ---------------------------------------------------------------------------
// k_fused: cooperative, 256 blocks x 512 thr, 1 block/CU (52.1KB LDS).
// Phase 0 = k_T, grid.sync, Phase 1 = k_pre (352 virtual blocks), grid.sync,
// Phase 2 = k_pre2 (32 vblocks), grid.sync, Phase 3 = k_chain (254 vblocks)
// + fused k_match. Each phase's body is line-identical to the round-6 best;
// only the block indexing changed. Removes 3 kernel drain/launch boundaries
// and makes this kernel visible in top-5 counters (it was hidden under the
// harness's 122µs fills before).
// ---------------------------------------------------------------------------
__global__ __launch_bounds__(512) void k_fused(KParams p)
{
  namespace cg = cooperative_groups;
  cg::grid_group grid = cg::this_grid();

  __shared__ float smf[16*132*6];   // 12672 floats = 50688 B
  __shared__ int   smi[352];

  const int tid = threadIdx.x;
  const int blk = blockIdx.x;
  const int gid = blk*512 + tid;
  const int gsz = 256*512;

  float* XA = smf;
  float* XB = smf + 2112;
  float* M1 = smf + 4224;
  float* M2 = smf + 6336;
  float* PB = smf + 8448;
  float* XC = smf + 10560;
  int* idx = smi;          // [160]
  int* n3  = smi + 160;    // [64]
  int* qts = smi + 224;    // [16]
  int* rts = smi + 240;    // [16]
  int* mts = smi + 256;    // [16]
  int* n1s = smi + 272;    // [64]

  // ======== phase 0: k_T (weight transposes, ER2, BIH, CPAD, zeroing) ======
  for (int i = gid; i < 49152; i += gsz) {
    int j = i >> 14, rem = i & 16383, k = rem >> 7, e = rem & 127;
    p.WT012[i] = p.W_agg[j*16384 + e*128 + k];
  }
  for (int i = gid; i < 16384; i += gsz) {
    int k = i >> 7, e = i & 127;
    p.WLT[i] = p.W_last[e*128 + k];
    p.WQT[i] = p.W_query[e*128 + k];
  }
  for (int i = gid; i < 65536; i += gsz) {
    int k = i >> 9, e = i & 511;
    p.WIHT[i] = p.W_ih[e*256 + k];
  }
  for (int i = gid; i < 1024; i += gsz) {
    int r = i >> 9, c = i & 511;
    const float* wcol = p.W_ih + (size_t)c*256 + 128;
    const float* er = p.emb_r + r*128;
    float acc = 0.f;
    #pragma unroll 4
    for (int k = 0; k < 128; k += 4) {
      acc = fmaf(er[k], wcol[k],
            fmaf(er[k+1], wcol[k+1],
            fmaf(er[k+2], wcol[k+2],
            fmaf(er[k+3], wcol[k+3], acc))));
    }
    p.ER2[i] = acc;
  }
  for (int i = gid; i < 65536; i += gsz) p.G1[i] = 0.f;
  if (gid < 512) p.BIH[gid] = p.b_ih[gid] + p.b_hh[gid];
  if (gid < 128) p.Pmaxi[gid] = 0;
  if (blk == 0) {
    float v = (tid < 128) ? ftanh(p.b_query[tid]) * p.w_W[128 + tid] : 0.f;
    if (tid < 256) smf[tid] = v;
    __syncthreads();
    #pragma unroll
    for (int s = 128; s > 0; s >>= 1) {
      if (tid < s) smf[tid] += smf[tid + s];
      __syncthreads();
    }
    if (tid == 0) p.CPAD[0] = smf[0];
  }
  grid.sync();

  // ======== phase 1: k_pre (352 virtual blocks: 32 E1 + 320 G1) ===========
  for (int vb = blk; vb < 352; vb += 256) {
    if (vb < 32) {
      const int s0 = vb*16;
      if (tid < 160) idx[tid] = p.s_neighbors[s0*10 + tid];
      __syncthreads();
      {
        const int e4 = (tid & 31) << 2;
        const int rr = tid >> 5;
        float4 a = ld4(p.emb_s + (size_t)(s0+rr)*128 + e4);
        float sx=0,sy=0,sz=0,sw=0;
        #pragma unroll
        for (int jj = 0; jj < 10; ++jj) {
          float4 q = ld4(p.emb_q + (size_t)idx[rr*10+jj]*128 + e4);
          sx+=q.x; sy+=q.y; sz+=q.z; sw+=q.w;
        }
        float4 o; o.x=a.x+0.1f*sx; o.y=a.y+0.1f*sy; o.z=a.z+0.1f*sz; o.w=a.w+0.1f*sw;
        *(float4*)(XA + rr*132 + e4) = o;
      }
      __syncthreads();
      gemmKS<128,132>(p.WT012 + 16384, 128, XA, p.b_agg + 128, XB, PB);
      __syncthreads();
      for (int f = tid; f < 2048; f += 512) {
        int r = f >> 7, e = f & 127, i = r*132 + e;
        p.E1[(size_t)(s0+r)*128 + e] = ftanh(XB[i] + PB[i]);
      }
      __syncthreads();
    } else {
      const int p0 = (vb-32)*16;
      if (tid < 16) idx[tid] = p.s_neighbors[p0 + tid];
      __syncthreads();
      if (tid < 64) n3[tid] = p.q_neighbors[(size_t)idx[tid>>2]*4 + (tid&3)];
      __syncthreads();
      {
        const int e4 = (tid & 31) << 2;
        const int rr = tid >> 5;
        float4 a = ld4(p.emb_q + (size_t)idx[rr]*128 + e4);
        float sx=0,sy=0,sz=0,sw=0;
        #pragma unroll
        for (int k = 0; k < 4; ++k) {
          float4 q = ld4(p.emb_s + (size_t)n3[rr*4+k]*128 + e4);
          sx+=q.x; sy+=q.y; sz+=q.z; sw+=q.w;
        }
        float4 o; o.x=a.x+0.25f*sx; o.y=a.y+0.25f*sy; o.z=a.z+0.25f*sz; o.w=a.w+0.25f*sw;
        *(float4*)(XA + rr*132 + e4) = o;
      }
      __syncthreads();
      gemmKS<128,132>(p.WT012 + 32768, 128, XA, p.b_agg + 256, XB, PB);
      __syncthreads();
      for (int f = tid; f < 2048; f += 512) {
        int r = f >> 7, e = f & 127, i = r*132 + e;
        atomicAdd(&p.G1[(size_t)((p0+r)/10)*128 + e], ftanh(XB[i] + PB[i]));
      }
      __syncthreads();
    }
  }
  grid.sync();

  // ======== phase 2: k_pre2 (32 virtual blocks) ============================
  if (blk < 32) {
    const int s0 = blk*16;
    for (int f = tid; f < 2048; f += 512) {
      int r = f >> 7, e = f & 127;
      XA[r*132 + e] = 0.1f*p.G1[(size_t)(s0+r)*128 + e] + p.E1[(size_t)(s0+r)*128 + e];
    }
    __syncthreads();
    gemmKS<128,132>(p.WT012 + 16384, 128, XA, p.b_agg + 128, XB, PB);
    __syncthreads();
    for (int f = tid; f < 2048; f += 512) {
      int r = f >> 7, e = f & 127, i = r*132 + e;
      p.E2[(size_t)(s0+r)*128 + e] = ftanh(XB[i] + PB[i]);
    }
  }
  grid.sync();

  // ======== phase 3: k_chain (254 virtual blocks) + fused k_match =========
  if (blk < 254) {
    if (tid < 16) {
      int rid = blk*16 + tid;
      int b = rid / 127, t = rid - b*127;
      qts[tid] = p.question[b*SEQ + t];
      rts[tid] = p.response[b*SEQ + t];
      mts[tid] = p.maskp[b*SEQ + t];
    }
    __syncthreads();
    if (tid < 64) n1s[tid] = p.q_neighbors[(size_t)qts[tid>>2]*4 + (tid&3)];
    __syncthreads();
    {
      const int e4 = (tid & 31) << 2;
      const int rr = tid >> 5;
      const int* nn = n1s + rr*4;
      float4 a = ld4(p.emb_q + (size_t)qts[rr]*128 + e4);
      float s1x=0,s1y=0,s1z=0,s1w=0, s2x=0,s2y=0,s2z=0,s2w=0, s3x=0,s3y=0,s3z=0,s3w=0;
      #pragma unroll
      for (int i = 0; i < 4; ++i) {
        float4 q1 = ld4(p.emb_s + (size_t)nn[i]*128 + e4);
        float4 q2 = ld4(p.E1 + (size_t)nn[i]*128 + e4);
        float4 q3 = ld4(p.E2 + (size_t)nn[i]*128 + e4);
        s1x+=q1.x; s1y+=q1.y; s1z+=q1.z; s1w+=q1.w;
        s2x+=q2.x; s2y+=q2.y; s2z+=q2.z; s2w+=q2.w;
        s3x+=q3.x; s3y+=q3.y; s3z+=q3.z; s3w+=q3.w;
      }
      float4 o; o.x=a.x+0.25f*s1x; o.y=a.y+0.25f*s1y; o.z=a.z+0.25f*s1z; o.w=a.w+0.25f*s1w;
      *(float4*)(XA + rr*132 + e4) = o;
      float4 pv; pv.x=0.25f*s2x; pv.y=0.25f*s2y; pv.z=0.25f*s2z; pv.w=0.25f*s2w;
      *(float4*)(M1 + rr*132 + e4) = pv;
      float4 u; u.x=0.25f*s3x; u.y=0.25f*s3y; u.z=0.25f*s3z; u.w=0.25f*s3w;
      *(float4*)(M2 + rr*132 + e4) = u;
    }
    __syncthreads();
    gemmKS<128,132>(p.WT012, 128, XA, p.b_agg, XB, PB);     // e0_1 pre-act
    __syncthreads();
    for (int f = tid; f < 2048; f += 512) {
      int i = (f >> 7)*132 + (f & 127);
      XB[i] = M1[i] + ftanh(XB[i] + PB[i]);
    }
    __syncthreads();
    gemmKS<128,132>(p.WT012, 128, XB, p.b_agg, XA, PB);     // e0_2 pre-act
    __syncthreads();
    for (int f = tid; f < 2048; f += 512) {
      int i = (f >> 7)*132 + (f & 127);
      XA[i] = M2[i] + ftanh(XA[i] + PB[i]);
    }
    __syncthreads();
    gemmKS<128,132>(p.WT012, 128, XA, p.b_agg, XB, PB);     // e0_3 pre-act
    __syncthreads();
    for (int f = tid; f < 2048; f += 512) {
      int i = (f >> 7)*132 + (f & 127);
      XB[i] = ftanh(XB[i] + PB[i]);
    }
    __syncthreads();
    gemmKS<128,132>(p.WLT, 128, XB, p.b_last, XA, PB);      // agg pre-act
    __syncthreads();
    for (int f = tid; f < 2048; f += 512) {
      int r = f >> 7, e = f & 127, i = r*132 + e;
      float agg = ftanh(XA[i] + PB[i]);
      XC[i] = (mts[r] == 1) ? agg : p.emb_q[(size_t)qts[r]*128 + e];
    }
    __syncthreads();
    gemmKS<128,132>(p.WIHT,       512, XC, p.BIH,       XA, PB);
    __syncthreads();
    for (int f = tid; f < 2048; f += 512) {
      int r = f >> 7, e = f & 127, i = r*132 + e;
      XA[i] += PB[i] + p.ER2[rts[r]*512 + e];
    }
    __syncthreads();
    gemmKS<128,132>(p.WIHT + 256, 512, XC, p.BIH + 256, XB, PB);
    __syncthreads();
    for (int f = tid; f < 2048; f += 512) {
      int r = f >> 7, e = f & 127, i = r*132 + e;
      XB[i] += PB[i] + p.ER2[rts[r]*512 + 256 + e];
    }
    __syncthreads();
    gemmKS<128,132>(p.WIHT + 384, 512, XC, p.BIH + 384, M1, PB);
    __syncthreads();
    for (int f = tid; f < 2048; f += 512) {
      int r = f >> 7, e = f & 127, i = r*132 + e;
      float gi = XA[i], gg = XB[i];
      float go = M1[i] + PB[i] + p.ER2[rts[r]*512 + 384 + e];
      float h = fsig(go) * ftanh(fsig(gi) * ftanh(gg));
      XC[i] = h;
      p.Hfull[(size_t)(blk*16 + r)*128 + e] = h;
    }
    __syncthreads();
    gemmKS<128,132>(p.WQT, 128, XC, p.b_query, XA, PB);     // c pre-act
    __syncthreads();
    {
      const int et = tid & 31, rr = tid >> 5;
      float4 wv = ld4(p.w_W + 128 + et*4);
      float4 o = ld4(XA + rr*132 + et*4);
      float4 pv = ld4(PB + rr*132 + et*4);
      float s = ftanh(o.x+pv.x)*wv.x + ftanh(o.y+pv.y)*wv.y
              + ftanh(o.z+pv.z)*wv.z + ftanh(o.w+pv.w)*wv.w;
      #pragma unroll
      for (int off = 16; off > 0; off >>= 1) s += __shfl_down(s, off);
      if (et == 0) p.Cq[blk*16 + rr] = s;
    }
    // ---- fused k_match: wave w handles rows w and w+8 ----
    {
      const int wv = tid >> 6;      // wave 0..7
      const int ln = tid & 63;      // lane 0..63
      for (int rr = wv; rr < 16; rr += 8) {
        int rid = blk*16 + rr;
        int b = rid / 127, t = rid - b*127;
        int q_next = p.question[b*SEQ + t + 1];
        int qrv = 0;
        if (ln < 40)
          qrv = p.s_neighbors[(size_t)p.q_neighbors[(size_t)q_next*4 + ln/10]*10 + ln%10];
        int q0 = p.question[b*SEQ + ln];
        int q1 = p.question[b*SEQ + 64 + ln];
        bool p0 = false, p1 = false;
        #pragma unroll 8
        for (int i = 0; i < 40; ++i) {
          int qv = __shfl(qrv, i);
          p0 |= (q0 == qv); p1 |= (q1 == qv);
        }
        p0 &= (ln < t);
        p1 &= (64 + ln < t);
        unsigned long long w0 = __ballot(p0);
        unsigned long long w1 = __ballot(p1);
        if (ln == 0) {
          size_t bt = (size_t)b*NSTEP + t;
          p.mwords[bt*2 + 0] = w0;
          p.mwords[bt*2 + 1] = w1;
          int ns = __popcll(w0) + __popcll(w1);
          p.nsel[bt] = ns;
          atomicMax(&p.Pmaxi[t], ns);
        }
      }
    }
  }
}

__device__ __forceinline__ float wredsum(float v) {
  #pragma unroll
  for (int o = 32; o > 0; o >>= 1) v += __shfl_down(v, o);
  return v;
}
__device__ __forceinline__ float wredmax(float v) {
  #pragma unroll
  for (int o = 32; o > 0; o >>= 1) v = fmaxf(v, __shfl_down(v, o));
  return v;
}

// ---------------------------------------------------------------------------
// k_attn: collapsed attention (a[q] cancels across the softmax), y -> out.
// Kept as a separate kernel: it wants 16 blocks/CU occupancy that the
// 52KB-LDS fused kernel cannot provide.
// ---------------------------------------------------------------------------
__global__ __launch_bounds__(128) void k_attn(
    const int* __restrict__ question, const float* __restrict__ qs_table,
    const float* __restrict__ emb_q, const float* __restrict__ emb_s,
    const float* __restrict__ CPAD,
    const float* __restrict__ Hfull, const float* __restrict__ Cq,
    const int* __restrict__ nsel, const unsigned long long* __restrict__ mwords,
    const int* __restrict__ Pmaxi, float* __restrict__ out)
{
  __shared__ float us[128];
  __shared__ int cols[8];
  __shared__ int cnt;
  __shared__ float smx[2];
  __shared__ float s3[2][3];
  const int tid = threadIdx.x;
  const int wid = tid >> 6;
  const int bid = blockIdx.x;
  const int b = bid / NSTEP, t = bid % NSTEP;
  const size_t bt = (size_t)b*NSTEP + t;
  const int q_next = question[b*SEQ + t + 1];

  if (tid == 0) cnt = 0;
  __syncthreads();
  {
    float4 v = ld4(qs_table + (size_t)q_next*NS + tid*4);
    if (v.x > 0.f) { int pp = atomicAdd(&cnt, 1); if (pp < 8) cols[pp] = tid*4; }
    if (v.y > 0.f) { int pp = atomicAdd(&cnt, 1); if (pp < 8) cols[pp] = tid*4+1; }
    if (v.z > 0.f) { int pp = atomicAdd(&cnt, 1); if (pp < 8) cols[pp] = tid*4+2; }
    if (v.w > 0.f) { int pp = atomicAdd(&cnt, 1); if (pp < 8) cols[pp] = tid*4+3; }
  }
  __syncthreads();
  const int nc = min(cnt, 4);
  {
    float ue = emb_q[(size_t)q_next*EMB + tid];
    for (int i = 0; i < nc; ++i) ue += emb_s[(size_t)cols[i]*EMB + tid];
    us[tid] = ue;
  }
  const float c_pad = CPAD[0];
  const float P = (float)(Pmaxi[t] - nsel[bt]);

  const unsigned long long w0 = mwords[bt*2 + 0];
  const unsigned long long w1 = mwords[bt*2 + 1];
  const bool matched = (tid < 64) ? ((w0 >> tid) & 1ull)
                                  : ((w1 >> (tid - 64)) & 1ull);
  const float c_cur = Cq[bt];
  float Cp = matched ? ((tid == 0) ? c_pad : Cq[(size_t)b*NSTEP + tid]) : -3.0e38f;
  float mh = wredmax(Cp);
  if ((tid & 63) == 0) smx[wid] = mh;
  __syncthreads();   // also publishes us[]
  float M = fmaxf(fmaxf(smx[0], smx[1]), fmaxf(c_cur, c_pad));
  float wgt = matched ? __expf(Cp - M) : 0.f;
  float dotp = 0.f;
  if (matched && tid >= 1) {  // p=0 history row is zeros
    const float* hp = Hfull + ((size_t)b*NSTEP + tid)*EMB;
    float s = 0.f;
    #pragma unroll 8
    for (int e = 0; e < 128; e += 4) {
      float4 h4 = ld4(hp + e);
      s = fmaf(us[e],h4.x, fmaf(us[e+1],h4.y, fmaf(us[e+2],h4.z, fmaf(us[e+3],h4.w, s))));
    }
    dotp = s;
  }
  float gcp = us[tid] * Hfull[bt*EMB + tid];
  float a0 = wredsum(wgt);
  float a1 = wredsum(wgt * dotp);
  float a2 = wredsum(gcp);
  if ((tid & 63) == 0) { s3[wid][0] = a0; s3[wid][1] = a1; s3[wid][2] = a2; }
  __syncthreads();
  if (tid == 0) {
    float Sexp = s3[0][0] + s3[1][0];
    float Snum = s3[0][1] + s3[1][1];
    float gc   = s3[0][2] + s3[1][2];
    float Ec = __expf(c_cur - M), Ep = __expf(c_pad - M);
    float D = Sexp + Ec + P * Ep;
    float numt = Snum + Ec * gc;
    out[b*SEQ + t + 1] = fsig(numt / D);
    if (t == 0) out[b*SEQ] = 0.5f;
  }
}

extern "C" void kernel_launch(void* const* d_in, const int* in_sizes, int n_in,
                              void* d_out, int out_size, void* d_ws, size_t ws_size,
                              hipStream_t stream) {
  const int* question    = (const int*)d_in[0];
  const int* response    = (const int*)d_in[1];
  const int* maskp       = (const int*)d_in[2];
  const int* q_neighbors = (const int*)d_in[3];
  const int* s_neighbors = (const int*)d_in[4];
  const float* qs_table  = (const float*)d_in[5];
  const float* emb_q     = (const float*)d_in[6];
  const float* emb_s     = (const float*)d_in[7];
  const float* emb_r     = (const float*)d_in[8];
  const float* W_ih      = (const float*)d_in[9];
  const float* b_ih      = (const float*)d_in[10];
  const float* b_hh      = (const float*)d_in[11];
  const float* W_agg     = (const float*)d_in[12];
  const float* b_agg     = (const float*)d_in[13];
  const float* W_last    = (const float*)d_in[14];
  const float* b_last    = (const float*)d_in[15];
  const float* W_query   = (const float*)d_in[16];
  const float* b_query   = (const float*)d_in[17];
  // d_in[18] W_key, d_in[19] b_key, d_in[21] b_W: no effect (a[q] cancels)
  const float* w_W       = (const float*)d_in[20];
  float* out = (float*)d_out;

  float* ws = (float*)d_ws;
  float* WT012 = ws;                    // 49152
  float* WLT   = ws + 49152;            // 16384
  float* WQT   = ws + 65536;            // 16384
  float* WIHT  = ws + 81920;            // 65536  [128][512] (h-half only)
  float* ER2   = ws + 147456;           // 1024   [2][512]
  float* BIH   = ws + 212992;           // 512
  float* CPAD  = ws + 213504;           // 16
  float* E1    = ws + 213520;           // 65536
  float* G1    = ws + 279056;           // 65536
  float* E2    = ws + 344592;           // 65536
  float* Hfull = ws + 410128;           // 520192
  float* Cq    = ws + 930320;           // 4064
  int*   Pmaxi = (int*)(ws + 934384);   // 128
  int*   nselp = (int*)(ws + 934512);   // 4064
  unsigned long long* mwords =
      (unsigned long long*)(((uintptr_t)(ws + 938576) + 15) & ~(uintptr_t)15);

  KParams p;
  p.question = question; p.response = response; p.maskp = maskp;
  p.q_neighbors = q_neighbors; p.s_neighbors = s_neighbors;
  p.emb_q = emb_q; p.emb_s = emb_s; p.emb_r = emb_r;
  p.W_agg = W_agg; p.W_last = W_last; p.W_query = W_query; p.W_ih = W_ih;
  p.b_ih = b_ih; p.b_hh = b_hh; p.b_agg = b_agg; p.b_last = b_last;
  p.b_query = b_query; p.w_W = w_W;
  p.WT012 = WT012; p.WLT = WLT; p.WQT = WQT; p.WIHT = WIHT; p.ER2 = ER2;
  p.BIH = BIH; p.CPAD = CPAD; p.E1 = E1; p.G1 = G1; p.E2 = E2;
  p.Hfull = Hfull; p.Cq = Cq; p.nsel = nselp; p.mwords = mwords;
  p.Pmaxi = Pmaxi;

  void* kargs[] = { (void*)&p };
  hipLaunchCooperativeKernel((const void*)k_fused, dim3(256), dim3(512),
                             kargs, 0, stream);
  k_attn<<<dim3(NB*NSTEP), dim3(128), 0, stream>>>(
      question, qs_table, emb_q, emb_s, CPAD, Hfull, Cq,
      nselp, mwords, Pmaxi, out);
}

// Round 8
// 381.175 us; speedup vs baseline: 1.3172x; 1.3172x over previous
//
#include <hip/hip_runtime.h>
#include <stdint.h>

#define NB 32
#define SEQ 128
#define EMB 128
#define NSTEP 127
#define NS 512

__device__ __forceinline__ float ftanh(float x){ float e=__expf(2.f*x); return 1.f-2.f/(e+1.f); }
__device__ __forceinline__ float fsig(float x){ return 1.f/(1.f+__expf(-x)); }
__device__ __forceinline__ float4 ld4(const float* p){ return *(const float4*)p; }

// ---------------------------------------------------------------------------
// Streamed-WT GEMM: out[r,e] = bias[e] + sum_k X[r,k] * WT[k,e]
// X in LDS [R][XS]; WT global row-major [K][NEtot] (pre-transposed).
// NAMED register double groups only — any VGPR array with non-constant index
// is demoted to scratch (prior session: 256 VGPR + 554 MB scratch traffic).
// ---------------------------------------------------------------------------
#define FMA4(acc, xv, a0, a1, a2, a3) \
  acc.x = fmaf(xv.x, a0.x, fmaf(xv.y, a1.x, fmaf(xv.z, a2.x, fmaf(xv.w, a3.x, acc.x)))); \
  acc.y = fmaf(xv.x, a0.y, fmaf(xv.y, a1.y, fmaf(xv.z, a2.y, fmaf(xv.w, a3.y, acc.y)))); \
  acc.z = fmaf(xv.x, a0.z, fmaf(xv.y, a1.z, fmaf(xv.z, a2.z, fmaf(xv.w, a3.z, acc.z)))); \
  acc.w = fmaf(xv.x, a0.w, fmaf(xv.y, a1.w, fmaf(xv.z, a2.w, fmaf(xv.w, a3.w, acc.w))));

// ---------------------------------------------------------------------------
// gemmKS: 512-thr blocks, K-SPLIT. et=tid&31 (4 cols, float4 loads),
// kt=(tid>>5)&1 (half of K each), rg=tid>>6 (8 groups x NR=2 rows = 16 rows).
// kt=0 adds bias and writes outb; kt=1 writes raw partial to partb.
// Caller must sum outb+partb after the following __syncthreads.
// ---------------------------------------------------------------------------
template<int K, int XS>
__device__ __forceinline__ void gemmKS(const float* __restrict__ WT, int NEtot,
                                       const float* Xl, const float* __restrict__ bias,
                                       float* outb, float* partb)
{
  const int tid = threadIdx.x;
  const int et = tid & 31;
  const int kt = (tid >> 5) & 1;
  const int rg = tid >> 6;                 // 0..7
  constexpr int KH = K/2;
  constexpr int G  = KH/4;
  const float* wp = WT + (size_t)kt*KH*NEtot + et*4;
  const float* xr = Xl + (size_t)(rg*2)*XS + kt*KH;
  float4 a0 = {0.f,0.f,0.f,0.f};
  float4 a1 = {0.f,0.f,0.f,0.f};
  float4 w0 = ld4(wp);
  float4 w1 = ld4(wp + NEtot);
  float4 w2 = ld4(wp + 2*NEtot);
  float4 w3 = ld4(wp + 3*NEtot);
  const float* wq = wp + (size_t)4*NEtot;
  float4 m0 = ld4(wq);
  float4 m1 = ld4(wq + NEtot);
  float4 m2 = ld4(wq + 2*NEtot);
  float4 m3 = ld4(wq + 3*NEtot);
  #pragma unroll 2
  for (int g = 0; g + 2 < G; g += 2) {
    const float* wa = wp + (size_t)(4*(g+2))*NEtot;
    float4 n0 = ld4(wa);
    float4 n1 = ld4(wa + NEtot);
    float4 n2 = ld4(wa + 2*NEtot);
    float4 n3 = ld4(wa + 3*NEtot);
    float4 xa0 = ld4(xr + 4*g);
    float4 xa1 = ld4(xr + XS + 4*g);
    FMA4(a0, xa0, w0, w1, w2, w3);
    FMA4(a1, xa1, w0, w1, w2, w3);
    w0=n0; w1=n1; w2=n2; w3=n3;
    const float* wb = wp + (size_t)(4*(g+3))*NEtot;
    float4 o0 = ld4(wb);
    float4 o1 = ld4(wb + NEtot);
    float4 o2 = ld4(wb + 2*NEtot);
    float4 o3 = ld4(wb + 3*NEtot);
    float4 xb0 = ld4(xr + 4*(g+1));
    float4 xb1 = ld4(xr + XS + 4*(g+1));
    FMA4(a0, xb0, m0, m1, m2, m3);
    FMA4(a1, xb1, m0, m1, m2, m3);
    m0=o0; m1=o1; m2=o2; m3=o3;
  }
  {
    float4 xa0 = ld4(xr + 4*(G-2));
    float4 xa1 = ld4(xr + XS + 4*(G-2));
    FMA4(a0, xa0, w0, w1, w2, w3);
    FMA4(a1, xa1, w0, w1, w2, w3);
    float4 xb0 = ld4(xr + 4*(G-1));
    float4 xb1 = ld4(xr + XS + 4*(G-1));
    FMA4(a0, xb0, m0, m1, m2, m3);
    FMA4(a1, xb1, m0, m1, m2, m3);
  }
  float* dst;
  if (kt == 0) {
    float4 bb = ld4(bias + et*4);
    a0.x+=bb.x; a0.y+=bb.y; a0.z+=bb.z; a0.w+=bb.w;
    a1.x+=bb.x; a1.y+=bb.y; a1.z+=bb.z; a1.w+=bb.w;
    dst = outb;
  } else {
    dst = partb;
  }
  float* ob = dst + (size_t)(rg*2)*132 + et*4;
  *(float4*)(ob)       = a0;
  *(float4*)(ob + 132) = a1;
}

// ---------------------------------------------------------------------------
// k_T: transpose weights into ws, BIH = b_ih+b_hh, c_pad, zero G1/Pmaxi.
// WIHT keeps only the h-half of W_ih (K=128); ER2[2][512] holds the
// precomputed emb_r-half contribution (r_t is binary).
// ---------------------------------------------------------------------------
__global__ __launch_bounds__(256) void k_T(
    const float* __restrict__ W_agg, const float* __restrict__ W_last,
    const float* __restrict__ W_query, const float* __restrict__ W_ih,
    const float* __restrict__ b_ih, const float* __restrict__ b_hh,
    const float* __restrict__ b_query, const float* __restrict__ w_W,
    const float* __restrict__ emb_r,
    float* __restrict__ WT012, float* __restrict__ WLT, float* __restrict__ WQT,
    float* __restrict__ WIHT, float* __restrict__ ER2,
    float* __restrict__ BIH, float* __restrict__ CPAD,
    float* __restrict__ G1, int* __restrict__ Pmaxi)
{
  const int gid = blockIdx.x*256 + threadIdx.x;
  const int gsz = gridDim.x*256;
  for (int i = gid; i < 49152; i += gsz) {
    int j = i >> 14, rem = i & 16383, k = rem >> 7, e = rem & 127;
    WT012[i] = W_agg[j*16384 + e*128 + k];
  }
  for (int i = gid; i < 16384; i += gsz) {
    int k = i >> 7, e = i & 127;
    WLT[i] = W_last[e*128 + k];
    WQT[i] = W_query[e*128 + k];
  }
  for (int i = gid; i < 65536; i += gsz) {
    int k = i >> 9, e = i & 511;
    WIHT[i] = W_ih[e*256 + k];
  }
  for (int i = gid; i < 1024; i += gsz) {
    int r = i >> 9, c = i & 511;
    const float* wcol = W_ih + (size_t)c*256 + 128;
    const float* er = emb_r + r*128;
    float acc = 0.f;
    #pragma unroll 4
    for (int k = 0; k < 128; k += 4) {
      acc = fmaf(er[k], wcol[k],
            fmaf(er[k+1], wcol[k+1],
            fmaf(er[k+2], wcol[k+2],
            fmaf(er[k+3], wcol[k+3], acc))));
    }
    ER2[i] = acc;
  }
  for (int i = gid; i < 65536; i += gsz) G1[i] = 0.f;
  if (gid < 512) BIH[gid] = b_ih[gid] + b_hh[gid];
  if (gid < 128) Pmaxi[gid] = 0;
  if (blockIdx.x == 0) {
    __shared__ float red[256];
    float v = (threadIdx.x < 128) ? ftanh(b_query[threadIdx.x]) * w_W[128 + threadIdx.x] : 0.f;
    red[threadIdx.x] = v; __syncthreads();
    #pragma unroll
    for (int s = 128; s > 0; s >>= 1) {
      if (threadIdx.x < s) red[threadIdx.x] += red[threadIdx.x + s];
      __syncthreads();
    }
    if (threadIdx.x == 0) CPAD[0] = red[0];
  }
}

// ---------------------------------------------------------------------------
// k_pre: 512-thr K-split blocks, 16 rows each. Blocks 0..31: E1.
// Blocks 32..351: 16 of 5120 (s,j) level-2 pairs, atomicAdd into G1.
// ---------------------------------------------------------------------------
__global__ __launch_bounds__(512) void k_pre(
    const int* __restrict__ s_neighbors, const int* __restrict__ q_neighbors,
    const float* __restrict__ emb_q, const float* __restrict__ emb_s,
    const float* __restrict__ WT012, const float* __restrict__ b_agg,
    float* __restrict__ E1, float* __restrict__ G1)
{
  __shared__ float XA[16*132];
  __shared__ float XB[16*132];
  __shared__ float PB[16*132];
  __shared__ int idx[160];
  __shared__ int n3[64];
  const int tid = threadIdx.x;
  const int blk = blockIdx.x;
  if (blk < 32) {
    const int s0 = blk*16;
    if (tid < 160) idx[tid] = s_neighbors[s0*10 + tid];
    __syncthreads();
    {
      const int e4 = (tid & 31) << 2;
      const int rr = tid >> 5;   // 0..15
      float4 a = ld4(emb_s + (size_t)(s0+rr)*128 + e4);
      float sx=0,sy=0,sz=0,sw=0;
      #pragma unroll
      for (int jj = 0; jj < 10; ++jj) {
        float4 q = ld4(emb_q + (size_t)idx[rr*10+jj]*128 + e4);
        sx+=q.x; sy+=q.y; sz+=q.z; sw+=q.w;
      }
      float4 o; o.x=a.x+0.1f*sx; o.y=a.y+0.1f*sy; o.z=a.z+0.1f*sz; o.w=a.w+0.1f*sw;
      *(float4*)(XA + rr*132 + e4) = o;
    }
    __syncthreads();
    gemmKS<128,132>(WT012 + 16384, 128, XA, b_agg + 128, XB, PB);
    __syncthreads();
    for (int f = tid; f < 2048; f += 512) {
      int r = f >> 7, e = f & 127, i = r*132 + e;
      E1[(size_t)(s0+r)*128 + e] = ftanh(XB[i] + PB[i]);
    }
  } else {
    const int p0 = (blk-32)*16;
    if (tid < 16) idx[tid] = s_neighbors[p0 + tid];
    __syncthreads();
    if (tid < 64) n3[tid] = q_neighbors[(size_t)idx[tid>>2]*4 + (tid&3)];
    __syncthreads();
    {
      const int e4 = (tid & 31) << 2;
      const int rr = tid >> 5;   // 0..15
      float4 a = ld4(emb_q + (size_t)idx[rr]*128 + e4);
      float sx=0,sy=0,sz=0,sw=0;
      #pragma unroll
      for (int k = 0; k < 4; ++k) {
        float4 q = ld4(emb_s + (size_t)n3[rr*4+k]*128 + e4);
        sx+=q.x; sy+=q.y; sz+=q.z; sw+=q.w;
      }
      float4 o; o.x=a.x+0.25f*sx; o.y=a.y+0.25f*sy; o.z=a.z+0.25f*sz; o.w=a.w+0.25f*sw;
      *(float4*)(XA + rr*132 + e4) = o;
    }
    __syncthreads();
    gemmKS<128,132>(WT012 + 32768, 128, XA, b_agg + 256, XB, PB);
    __syncthreads();
    for (int f = tid; f < 2048; f += 512) {
      int r = f >> 7, e = f & 127, i = r*132 + e;
      atomicAdd(&G1[(size_t)((p0+r)/10)*128 + e], ftanh(XB[i] + PB[i]));
    }
  }
}

// k_pre2: E2[s] = tanh((0.1*G1[s] + E1[s]) @ W1.T + b1)  (32 blocks x 16 rows)
__global__ __launch_bounds__(512) void k_pre2(
    const float* __restrict__ E1, const float* __restrict__ G1,
    const float* __restrict__ WT012, const float* __restrict__ b_agg,
    float* __restrict__ E2)
{
  __shared__ float XA[16*132];
  __shared__ float XB[16*132];
  __shared__ float PB[16*132];
  const int tid = threadIdx.x;
  const int s0 = blockIdx.x*16;
  for (int f = tid; f < 2048; f += 512) {
    int r = f >> 7, e = f & 127;
    XA[r*132 + e] = 0.1f*G1[(size_t)(s0+r)*128 + e] + E1[(size_t)(s0+r)*128 + e];
  }
  __syncthreads();
  gemmKS<128,132>(WT012 + 16384, 128, XA, b_agg + 128, XB, PB);
  __syncthreads();
  for (int f = tid; f < 2048; f += 512) {
    int r = f >> 7, e = f & 127, i = r*132 + e;
    E2[(size_t)(s0+r)*128 + e] = ftanh(XB[i] + PB[i]);
  }
}

// ---------------------------------------------------------------------------
// k_chain: 254 blocks x 512 thr x 16 (b,t)-rows, K-split gemms.
// LSTM gates K=128 (h-half only); emb_r-half from ER2 table.
// LDS 50.9KB. Fused k_match at the tail (8 waves x 2 rows).
// ---------------------------------------------------------------------------
__global__ __launch_bounds__(512) void k_chain(
    const int* __restrict__ question, const int* __restrict__ response,
    const int* __restrict__ maskp, const int* __restrict__ q_neighbors,
    const int* __restrict__ s_neighbors,
    const float* __restrict__ emb_q, const float* __restrict__ emb_s,
    const float* __restrict__ WT012, const float* __restrict__ WLT,
    const float* __restrict__ WQT, const float* __restrict__ WIHT,
    const float* __restrict__ ER2, const float* __restrict__ BIH,
    const float* __restrict__ b_agg, const float* __restrict__ b_last,
    const float* __restrict__ b_query, const float* __restrict__ w_W,
    const float* __restrict__ E1, const float* __restrict__ E2,
    float* __restrict__ Hfull, float* __restrict__ Cq,
    int* __restrict__ nsel, unsigned long long* __restrict__ mwords,
    int* __restrict__ Pmaxi)
{
  __shared__ float XA[16*132];
  __shared__ float XB[16*132];
  __shared__ float M1[16*132];
  __shared__ float M2[16*132];
  __shared__ float PB[16*132];   // K-split partial
  __shared__ float XC[16*132];   // h only (emb_r half replaced by ER2 table)
  __shared__ int qts[16], rts[16], mts[16], n1s[64];

  const int tid = threadIdx.x;
  const int blk = blockIdx.x;

  if (tid < 16) {
    int rid = blk*16 + tid;
    int b = rid / 127, t = rid - b*127;
    qts[tid] = question[b*SEQ + t];
    rts[tid] = response[b*SEQ + t];
    mts[tid] = maskp[b*SEQ + t];
  }
  __syncthreads();
  if (tid < 64) n1s[tid] = q_neighbors[(size_t)qts[tid>>2]*4 + (tid&3)];
  __syncthreads();
  // XA = emb_q[qt] + 0.25*sum emb_s[n1]; M1 = 0.25*sum E1[n1]; M2 = 0.25*sum E2[n1]
  {
    const int e4 = (tid & 31) << 2;
    const int rr = tid >> 5;   // 0..15
    const int* nn = n1s + rr*4;
    float4 a = ld4(emb_q + (size_t)qts[rr]*128 + e4);
    float s1x=0,s1y=0,s1z=0,s1w=0, s2x=0,s2y=0,s2z=0,s2w=0, s3x=0,s3y=0,s3z=0,s3w=0;
    #pragma unroll
    for (int i = 0; i < 4; ++i) {
      float4 q1 = ld4(emb_s + (size_t)nn[i]*128 + e4);
      float4 q2 = ld4(E1 + (size_t)nn[i]*128 + e4);
      float4 q3 = ld4(E2 + (size_t)nn[i]*128 + e4);
      s1x+=q1.x; s1y+=q1.y; s1z+=q1.z; s1w+=q1.w;
      s2x+=q2.x; s2y+=q2.y; s2z+=q2.z; s2w+=q2.w;
      s3x+=q3.x; s3y+=q3.y; s3z+=q3.z; s3w+=q3.w;
    }
    float4 o; o.x=a.x+0.25f*s1x; o.y=a.y+0.25f*s1y; o.z=a.z+0.25f*s1z; o.w=a.w+0.25f*s1w;
    *(float4*)(XA + rr*132 + e4) = o;
    float4 p; p.x=0.25f*s2x; p.y=0.25f*s2y; p.z=0.25f*s2z; p.w=0.25f*s2w;
    *(float4*)(M1 + rr*132 + e4) = p;
    float4 u; u.x=0.25f*s3x; u.y=0.25f*s3y; u.z=0.25f*s3z; u.w=0.25f*s3w;
    *(float4*)(M2 + rr*132 + e4) = u;
  }
  // 3-stage aggregation chain (each act-loop also merges the K-split partial)
  __syncthreads();
  gemmKS<128,132>(WT012, 128, XA, b_agg, XB, PB);     // e0_1 pre-act
  __syncthreads();
  for (int f = tid; f < 2048; f += 512) {
    int i = (f >> 7)*132 + (f & 127);
    XB[i] = M1[i] + ftanh(XB[i] + PB[i]);
  }
  __syncthreads();
  gemmKS<128,132>(WT012, 128, XB, b_agg, XA, PB);     // e0_2 pre-act
  __syncthreads();
  for (int f = tid; f < 2048; f += 512) {
    int i = (f >> 7)*132 + (f & 127);
    XA[i] = M2[i] + ftanh(XA[i] + PB[i]);
  }
  __syncthreads();
  gemmKS<128,132>(WT012, 128, XA, b_agg, XB, PB);     // e0_3 pre-act
  __syncthreads();
  for (int f = tid; f < 2048; f += 512) {
    int i = (f >> 7)*132 + (f & 127);
    XB[i] = ftanh(XB[i] + PB[i]);
  }
  __syncthreads();
  gemmKS<128,132>(WLT, 128, XB, b_last, XA, PB);      // agg pre-act
  __syncthreads();
  for (int f = tid; f < 2048; f += 512) {
    int r = f >> 7, e = f & 127, i = r*132 + e;
    float agg = ftanh(XA[i] + PB[i]);
    XC[i] = (mts[r] == 1) ? agg : emb_q[(size_t)qts[r]*128 + e];
  }
  __syncthreads();
  // LSTM gates gi/gg/go, K=128 (h part); emb_r part from ER2 table.
  gemmKS<128,132>(WIHT,       512, XC, BIH,       XA, PB);
  __syncthreads();
  for (int f = tid; f < 2048; f += 512) {
    int r = f >> 7, e = f & 127, i = r*132 + e;
    XA[i] += PB[i] + ER2[rts[r]*512 + e];
  }
  __syncthreads();
  gemmKS<128,132>(WIHT + 256, 512, XC, BIH + 256, XB, PB);
  __syncthreads();
  for (int f = tid; f < 2048; f += 512) {
    int r = f >> 7, e = f & 127, i = r*132 + e;
    XB[i] += PB[i] + ER2[rts[r]*512 + 256 + e];
  }
  __syncthreads();
  gemmKS<128,132>(WIHT + 384, 512, XC, BIH + 384, M1, PB);
  __syncthreads();
  for (int f = tid; f < 2048; f += 512) {
    int r = f >> 7, e = f & 127, i = r*132 + e;
    float gi = XA[i], gg = XB[i];
    float go = M1[i] + PB[i] + ER2[rts[r]*512 + 384 + e];
    float h = fsig(go) * ftanh(fsig(gi) * ftanh(gg));
    XC[i] = h;
    Hfull[(size_t)(blk*16 + r)*128 + e] = h;
  }
  __syncthreads();
  gemmKS<128,132>(WQT, 128, XC, b_query, XA, PB);     // c pre-act
  __syncthreads();
  {
    const int et = tid & 31, rr = tid >> 5;   // 16 rows exactly
    float4 wv = ld4(w_W + 128 + et*4);
    float4 o = ld4(XA + rr*132 + et*4);
    float4 p = ld4(PB + rr*132 + et*4);
    float s = ftanh(o.x+p.x)*wv.x + ftanh(o.y+p.y)*wv.y
            + ftanh(o.z+p.z)*wv.z + ftanh(o.w+p.w)*wv.w;
    #pragma unroll
    for (int off = 16; off > 0; off >>= 1) s += __shfl_down(s, off);
    if (et == 0) Cq[blk*16 + rr] = s;
  }
  // ---- fused k_match: wave w handles rows w and w+8 ----
  {
    const int wv = tid >> 6;      // wave 0..7
    const int ln = tid & 63;      // lane 0..63
    for (int rr = wv; rr < 16; rr += 8) {
      int rid = blk*16 + rr;
      int b = rid / 127, t = rid - b*127;
      int q_next = question[b*SEQ + t + 1];
      int qrv = 0;
      if (ln < 40)
        qrv = s_neighbors[(size_t)q_neighbors[(size_t)q_next*4 + ln/10]*10 + ln%10];
      int q0 = question[b*SEQ + ln];
      int q1 = question[b*SEQ + 64 + ln];
      bool p0 = false, p1 = false;
      #pragma unroll 8
      for (int i = 0; i < 40; ++i) {
        int qv = __shfl(qrv, i);
        p0 |= (q0 == qv); p1 |= (q1 == qv);
      }
      p0 &= (ln < t);
      p1 &= (64 + ln < t);
      unsigned long long w0 = __ballot(p0);
      unsigned long long w1 = __ballot(p1);
      if (ln == 0) {
        size_t bt = (size_t)b*NSTEP + t;
        mwords[bt*2 + 0] = w0;
        mwords[bt*2 + 1] = w1;
        int ns = __popcll(w0) + __popcll(w1);
        nsel[bt] = ns;
        atomicMax(&Pmaxi[t], ns);
      }
    }
  }
}

__device__ __forceinline__ float xsum(float v) {
  #pragma unroll
  for (int o = 32; o > 0; o >>= 1) v += __shfl_xor(v, o);
  return v;
}
__device__ __forceinline__ float xmax(float v) {
  #pragma unroll
  for (int o = 32; o > 0; o >>= 1) v = fmaxf(v, __shfl_xor(v, o));
  return v;
}

// ---------------------------------------------------------------------------
// k_attn: wave-per-(b,t), BARRIER-FREE. 508 blocks x 512 thr = 8 waves x
// 8 pairs. Replaces the 4064x128thr version (4 __syncthreads + LDS atomics):
// cols via 8 __ballot + uniform bit-scan; reductions via __shfl_xor; the
// matched path (Cq row, max-reduce, H-dots) skipped behind a wave-uniform
// (w0|w1)==0 fast path — expected matches ~0.05/row, so this is the ~always
// path. 8x fewer workgroups, no barriers, wave-private LDS only for us[].
// ---------------------------------------------------------------------------
__global__ __launch_bounds__(512) void k_attn(
    const int* __restrict__ question, const float* __restrict__ qs_table,
    const float* __restrict__ emb_q, const float* __restrict__ emb_s,
    const float* __restrict__ CPAD,
    const float* __restrict__ Hfull, const float* __restrict__ Cq,
    const int* __restrict__ nsel, const unsigned long long* __restrict__ mwords,
    const int* __restrict__ Pmaxi, float* __restrict__ out)
{
  __shared__ float us[8][128];
  const int tid = threadIdx.x;
  const int wv = tid >> 6;      // wave 0..7
  const int ln = tid & 63;      // lane 0..63
  const int pid = blockIdx.x*8 + wv;      // (b,t) pair, 0..4063
  const int b = pid / NSTEP, t = pid - b*NSTEP;
  const size_t bt = (size_t)b*NSTEP + t;
  const int q_next = question[b*SEQ + t + 1];

  // --- find the <=4 support cols of qs_table[q_next] via ballots (no LDS) ---
  float4 v0 = ld4(qs_table + (size_t)q_next*NS + ln*4);
  float4 v1 = ld4(qs_table + (size_t)q_next*NS + 256 + ln*4);
  unsigned long long m0b = __ballot(v0.x > 0.f);
  unsigned long long m1b = __ballot(v0.y > 0.f);
  unsigned long long m2b = __ballot(v0.z > 0.f);
  unsigned long long m3b = __ballot(v0.w > 0.f);
  unsigned long long m4b = __ballot(v1.x > 0.f);
  unsigned long long m5b = __ballot(v1.y > 0.f);
  unsigned long long m6b = __ballot(v1.z > 0.f);
  unsigned long long m7b = __ballot(v1.w > 0.f);

  float ue0 = emb_q[(size_t)q_next*EMB + ln];
  float ue1 = emb_q[(size_t)q_next*EMB + 64 + ln];
  {
    int added = 0;
    unsigned long long mm[1];
    #define SCAN(MB, KOFF, BASE) \
      { unsigned long long m = MB; \
        while (m && added < 4) { \
          int i = __ffsll((unsigned long long)m) - 1; m &= m - 1ull; \
          int c = BASE + i*4 + KOFF; \
          ue0 += emb_s[(size_t)c*EMB + ln]; \
          ue1 += emb_s[(size_t)c*EMB + 64 + ln]; \
          ++added; } }
    SCAN(m0b, 0, 0) SCAN(m1b, 1, 0) SCAN(m2b, 2, 0) SCAN(m3b, 3, 0)
    SCAN(m4b, 0, 256) SCAN(m5b, 1, 256) SCAN(m6b, 2, 256) SCAN(m7b, 3, 256)
    #undef SCAN
    (void)mm;
  }
  us[wv][ln] = ue0;
  us[wv][64 + ln] = ue1;

  const float c_pad = CPAD[0];
  const float P = (float)(Pmaxi[t] - nsel[bt]);
  const float c_cur = Cq[bt];
  const unsigned long long w0 = mwords[bt*2 + 0];
  const unsigned long long w1 = mwords[bt*2 + 1];

  // gc = us . Hfull[bt]  (always needed)
  float gcp = ue0*Hfull[bt*EMB + ln] + ue1*Hfull[bt*EMB + 64 + ln];
  float gc = xsum(gcp);

  float M, Sexp = 0.f, Snum = 0.f;
  if ((w0 | w1) == 0ull) {            // wave-uniform fast path: no matches
    M = fmaxf(c_cur, c_pad);
  } else {
    const bool ma = (w0 >> ln) & 1ull;          // history row p = ln
    const bool mb = (w1 >> ln) & 1ull;          // history row p = 64+ln
    float Cp0 = ma ? ((ln == 0) ? c_pad : Cq[(size_t)b*NSTEP + ln]) : -3.0e38f;
    float Cp1 = mb ? Cq[(size_t)b*NSTEP + 64 + ln] : -3.0e38f;
    float mh = xmax(fmaxf(Cp0, Cp1));
    M = fmaxf(mh, fmaxf(c_cur, c_pad));
    float wgt0 = ma ? __expf(Cp0 - M) : 0.f;
    float wgt1 = mb ? __expf(Cp1 - M) : 0.f;
    __threadfence_block();   // publish us[wv][] before cross-lane reads
    float d0 = 0.f, d1 = 0.f;
    if (ma && ln >= 1) {     // p=0 history row is zeros
      const float* hp = Hfull + ((size_t)b*NSTEP + ln)*EMB;
      const float* uu = us[wv];
      float s = 0.f;
      #pragma unroll 8
      for (int e = 0; e < 128; e += 4) {
        float4 h4 = ld4(hp + e);
        s = fmaf(uu[e],h4.x, fmaf(uu[e+1],h4.y, fmaf(uu[e+2],h4.z, fmaf(uu[e+3],h4.w, s))));
      }
      d0 = s;
    }
    if (mb) {
      const float* hp = Hfull + ((size_t)b*NSTEP + 64 + ln)*EMB;
      const float* uu = us[wv];
      float s = 0.f;
      #pragma unroll 8
      for (int e = 0; e < 128; e += 4) {
        float4 h4 = ld4(hp + e);
        s = fmaf(uu[e],h4.x, fmaf(uu[e+1],h4.y, fmaf(uu[e+2],h4.z, fmaf(uu[e+3],h4.w, s))));
      }
      d1 = s;
    }
    Sexp = xsum(wgt0 + wgt1);
    Snum = xsum(fmaf(wgt0, d0, wgt1 * d1));
  }
  if (ln == 0) {
    float Ec = __expf(c_cur - M), Ep = __expf(c_pad - M);
    float D = Sexp + Ec + P * Ep;
    float numt = Snum + Ec * gc;
    out[b*SEQ + t + 1] = fsig(numt / D);
    if (t == 0) out[b*SEQ] = 0.5f;
  }
}

extern "C" void kernel_launch(void* const* d_in, const int* in_sizes, int n_in,
                              void* d_out, int out_size, void* d_ws, size_t ws_size,
                              hipStream_t stream) {
  const int* question    = (const int*)d_in[0];
  const int* response    = (const int*)d_in[1];
  const int* maskp       = (const int*)d_in[2];
  const int* q_neighbors = (const int*)d_in[3];
  const int* s_neighbors = (const int*)d_in[4];
  const float* qs_table  = (const float*)d_in[5];
  const float* emb_q     = (const float*)d_in[6];
  const float* emb_s     = (const float*)d_in[7];
  const float* emb_r     = (const float*)d_in[8];
  const float* W_ih      = (const float*)d_in[9];
  const float* b_ih      = (const float*)d_in[10];
  const float* b_hh      = (const float*)d_in[11];
  const float* W_agg     = (const float*)d_in[12];
  const float* b_agg     = (const float*)d_in[13];
  const float* W_last    = (const float*)d_in[14];
  const float* b_last    = (const float*)d_in[15];
  const float* W_query   = (const float*)d_in[16];
  const float* b_query   = (const float*)d_in[17];
  // d_in[18] W_key, d_in[19] b_key, d_in[21] b_W: no effect (a[q] cancels)
  const float* w_W       = (const float*)d_in[20];
  float* out = (float*)d_out;

  float* ws = (float*)d_ws;
  float* WT012 = ws;                    // 49152
  float* WLT   = ws + 49152;            // 16384
  float* WQT   = ws + 65536;            // 16384
  float* WIHT  = ws + 81920;            // 65536  [128][512] (h-half only)
  float* ER2   = ws + 147456;           // 1024   [2][512]
  float* BIH   = ws + 212992;           // 512
  float* CPAD  = ws + 213504;           // 16
  float* E1    = ws + 213520;           // 65536
  float* G1    = ws + 279056;           // 65536
  float* E2    = ws + 344592;           // 65536
  float* Hfull = ws + 410128;           // 520192
  float* Cq    = ws + 930320;           // 4064
  int*   Pmaxi = (int*)(ws + 934384);   // 128
  int*   nselp = (int*)(ws + 934512);   // 4064
  unsigned long long* mwords =
      (unsigned long long*)(((uintptr_t)(ws + 938576) + 15) & ~(uintptr_t)15);

  k_T<<<dim3(512), dim3(256), 0, stream>>>(
      W_agg, W_last, W_query, W_ih, b_ih, b_hh, b_query, w_W, emb_r,
      WT012, WLT, WQT, WIHT, ER2, BIH, CPAD, G1, Pmaxi);
  k_pre<<<dim3(352), dim3(512), 0, stream>>>(
      s_neighbors, q_neighbors, emb_q, emb_s, WT012, b_agg, E1, G1);
  k_pre2<<<dim3(32), dim3(512), 0, stream>>>(E1, G1, WT012, b_agg, E2);
  k_chain<<<dim3(254), dim3(512), 0, stream>>>(
      question, response, maskp, q_neighbors, s_neighbors, emb_q, emb_s,
      WT012, WLT, WQT, WIHT, ER2, BIH, b_agg, b_last, b_query, w_W,
      E1, E2, Hfull, Cq, nselp, mwords, Pmaxi);
  k_attn<<<dim3(508), dim3(512), 0, stream>>>(
      question, qs_table, emb_q, emb_s, CPAD, Hfull, Cq,
      nselp, mwords, Pmaxi, out);
}